// Round 14
// baseline (301.788 us; speedup 1.0000x reference)
//
#include <hip/hip_runtime.h>
#include <math.h>

#define BIGF 1e10f
#define EPSF 1e-5f

typedef _Float16 f16;
typedef f16 f16x8 __attribute__((ext_vector_type(8)));
typedef float f32x4 __attribute__((ext_vector_type(4)));

static __device__ __forceinline__ f16x8 mk8(uint a, uint b, uint c, uint d) {
    union { uint u[4]; f16x8 v; } t;
    t.u[0] = a; t.u[1] = b; t.u[2] = c; t.u[3] = d;
    return t.v;
}

// ---------------------------------------------------------------------------
// Prepack: fold BN; conv3 B-frags [layer4][tap9][nt4][kf2][hl2][512],
// conv1 B-frags [kh7][nt4][hl2][512] (k = ic*8+kw, ic>=3 / kw==7 -> 0),
// biases b3[256], b1[64].  (unchanged, verified)
// ---------------------------------------------------------------------------
__global__ __launch_bounds__(256) void prepack(
    const float* __restrict__ c1w,
    const float* __restrict__ bn1g, const float* __restrict__ bn1b,
    const float* __restrict__ bn1m, const float* __restrict__ bn1v,
    const float* __restrict__ blkw,
    const float* __restrict__ blkg, const float* __restrict__ blkb,
    const float* __restrict__ blkm, const float* __restrict__ blkv,
    f16* __restrict__ wB, f16* __restrict__ wB1,
    float* __restrict__ b3, float* __restrict__ b1)
{
    int idx = blockIdx.x * 256 + threadIdx.x;
    if (idx < 147456) {                    // conv3 weight frags
        int pos = idx;
        int j    = pos & 7;
        int lane = (pos >> 3) & 63;
        int rest = pos >> 9;               // (((layer*9+tap)*4+nt)*2+kf)
        int kf   = rest & 1;
        int r2   = rest >> 1;
        int ntl  = r2 & 3;
        int r3   = r2 >> 2;
        int tap  = r3 % 9;
        int layer= r3 / 9;
        int ic = kf * 32 + (lane >> 4) * 8 + j;
        int oc = ntl * 16 + (lane & 15);
        float s = blkg[layer * 64 + oc] * rsqrtf(blkv[layer * 64 + oc] + EPSF);
        float wv = blkw[(((size_t)layer * 64 + oc) * 64 + ic) * 9 + tap] * s;
        f16 h = (f16)wv;
        f16 lo = (f16)(wv - (float)h);
        int low9 = pos & 511;
        wB[(size_t)rest * 1024 + low9]       = h;
        wB[(size_t)rest * 1024 + 512 + low9] = lo;
    }
    int q = idx - 147456;
    if (q >= 0 && q < 28672) {             // conv1 frags
        int j = q & 7, lane = (q >> 3) & 63, rest = q >> 9;  // ((kh*4+nt)*2+hl)
        int hl = rest & 1, nt = (rest >> 1) & 3, kh = rest >> 3;
        int oc = nt * 16 + (lane & 15), lgq = lane >> 4;
        float v = 0.f;
        if (lgq < 3 && j < 7) {
            float s = bn1g[oc] * rsqrtf(bn1v[oc] + EPSF);
            v = c1w[((oc * 3 + lgq) * 7 + kh) * 7 + j] * s;
        }
        f16 h = (f16)v;
        wB1[q] = hl ? (f16)(v - (float)h) : h;
    }
    int k = idx - 147456 - 28672;
    if (k >= 0 && k < 256) {
        float s = blkg[k] * rsqrtf(blkv[k] + EPSF);
        b3[k] = blkb[k] - blkm[k] * s;
    }
    int l = idx - 147456 - 28672 - 256;
    if (l >= 0 && l < 64) {
        float s = bn1g[l] * rsqrtf(bn1v[l] + EPSF);
        b1[l] = bn1b[l] - bn1m[l] * s;
    }
}

// ---------------------------------------------------------------------------
// conv1 7x7 s2 p3 + foldedBN + ReLU + maxpool via f16-split MFMA.
// (R9-verified: acc fully register-resident, epilogue og-loop unrolled)
// ---------------------------------------------------------------------------
__global__ __launch_bounds__(256) void conv1_mfma(
    const float* __restrict__ x, const f16* __restrict__ wB1,
    const float* __restrict__ bias,
    f16* __restrict__ outh, f16* __restrict__ outl)
{
    __shared__ char lds[18720];
    const int g = blockIdx.x, b = blockIdx.y;
    const int tid = threadIdx.x;
    const int w = tid >> 6, l = tid & 63;
    const int l15 = l & 15, lg = l >> 4;

    // ---- stage input rows 8g-5..8g+9 as f16 h/l planes [3][15][104] ----
    for (int i = tid; i < 4680; i += 256) ((uint*)lds)[i] = 0u;
    __syncthreads();
    const int ir0 = 8 * g - 5;
    const float* xb = x + (size_t)b * 27648;
    for (int u = tid; u < 2205; u += 256) {
        int cu = 1 + (u % 49);              // u32 col-pair: halves 2cu,2cu+1
        int rr = (u / 49) % 15;
        int ic = u / 735;
        int ir = ir0 + rr;
        uint pk_h = 0u, pk_l = 0u;
        if ((unsigned)ir < 96u) {
            int c0i = 2 * cu - 3, c1i = 2 * cu - 2;   // input cols
            const float* rowp = xb + ic * 9216 + ir * 96;
            float v0 = (c0i >= 0) ? rowp[c0i] : 0.f;
            float v1 = (c1i <= 95) ? rowp[c1i] : 0.f;
            f16 h0 = (f16)v0; f16 lo0 = (f16)(v0 - (float)h0);
            f16 h1 = (f16)v1; f16 lo1 = (f16)(v1 - (float)h1);
            union { f16 f[2]; uint u32; } ph, pl;
            ph.f[0] = h0;  ph.f[1] = h1;  pk_h = ph.u32;
            pl.f[0] = lo0; pl.f[1] = lo1; pk_l = pl.u32;
        }
        int off = ic * 3120 + rr * 208 + 4 * cu;
        *(uint*)(lds + off) = pk_h;
        *(uint*)(lds + 9360 + off) = pk_l;
    }
    __syncthreads();

    // ---- MFMA main: 7 kh x (bh sub-pass + bl sub-pass) x 4 tiles x 4 nt ----
    f32x4 acc[4][4];
#pragma unroll
    for (int k = 0; k < 4; ++k)
#pragma unroll
        for (int nt = 0; nt < 4; ++nt) acc[k][nt] = (f32x4){0.f, 0.f, 0.f, 0.f};

    const int icB = (lg >= 3 ? 0 : lg) * 3120;
    const char* hbase = lds + icB;
    const char* lbase = lds + 9360 + icB;
    const f16* wq = wB1 + (size_t)l * 8;

    int rowoff[4], aoff[4];
#pragma unroll
    for (int k = 0; k < 4; ++k) {
        int t = w + 4 * k;
        int tt = (t < 15) ? t : 0;
        rowoff[k] = tt / 3;                       // conv-row-local 0..4
        aoff[k] = 4 * ((tt % 3) * 16 + l15);      // byte col offset
    }

#pragma unroll 1
    for (int kh = 0; kh < 7; ++kh) {
        const f16* wk = wq + kh * 4096;
        f16x8 bq[4];
        // sub-pass 1: bh  (ah*bh + al*bh)
#pragma unroll
        for (int nt = 0; nt < 4; ++nt)
            bq[nt] = *(const f16x8*)(const void*)(wk + nt * 1024);
#pragma unroll
        for (int k = 0; k < 4; ++k) {
            if (w + 4 * k < 15) {
                int ro = (2 * rowoff[k] + kh) * 208 + aoff[k];
                const uint* ph = (const uint*)(hbase + ro);
                const uint* pl = (const uint*)(lbase + ro);
                f16x8 ah = mk8(ph[0], ph[1], ph[2], ph[3]);
                f16x8 al = mk8(pl[0], pl[1], pl[2], pl[3]);
#pragma unroll
                for (int nt = 0; nt < 4; ++nt) {
                    acc[k][nt] = __builtin_amdgcn_mfma_f32_16x16x32_f16(ah, bq[nt], acc[k][nt], 0, 0, 0);
                    acc[k][nt] = __builtin_amdgcn_mfma_f32_16x16x32_f16(al, bq[nt], acc[k][nt], 0, 0, 0);
                }
            }
        }
        // sub-pass 2: bl  (ah*bl)
#pragma unroll
        for (int nt = 0; nt < 4; ++nt)
            bq[nt] = *(const f16x8*)(const void*)(wk + nt * 1024 + 512);
#pragma unroll
        for (int k = 0; k < 4; ++k) {
            if (w + 4 * k < 15) {
                int ro = (2 * rowoff[k] + kh) * 208 + aoff[k];
                const uint* ph = (const uint*)(hbase + ro);
                f16x8 ah = mk8(ph[0], ph[1], ph[2], ph[3]);
#pragma unroll
                for (int nt = 0; nt < 4; ++nt)
                    acc[k][nt] = __builtin_amdgcn_mfma_f32_16x16x32_f16(ah, bq[nt], acc[k][nt], 0, 0, 0);
            }
        }
    }

    // ---- pool epilogue: 4 oc-group phases via [5][48][17] f32 plane ----
    __syncthreads();                       // staging planes dead
    float* pbuf = (float*)(void*)lds;
#pragma unroll
    for (int og = 0; og < 4; ++og) {
        float bi = bias[og * 16 + l15];
#pragma unroll
        for (int k = 0; k < 4; ++k) {
            int t = w + 4 * k;
            if (t < 15) {
                int lr = t / 3;
                int c0 = (t % 3) * 16;
#pragma unroll
                for (int r = 0; r < 4; ++r) {
                    int col = c0 + lg * 4 + r;
                    pbuf[(lr * 48 + col) * 17 + l15] = fmaxf(acc[k][og][r] + bi, 0.f);
                }
            }
        }
        __syncthreads();
#pragma unroll
        for (int it = 0; it < 3; ++it) {
            int idx = tid + it * 256;
            int oc = idx & 15, p2 = idx >> 4;       // p2 0..47
            int pc2 = p2 % 24, pr2 = p2 / 24;       // 2 pool rows x 24 cols
            float m = -INFINITY;
#pragma unroll
            for (int kr = 0; kr < 3; ++kr) {
                int lr = 2 * pr2 + kr;              // local conv row 0..4
                if (g == 0 && lr == 0) continue;    // conv row -1 (pad)
#pragma unroll
                for (int kc = 0; kc < 3; ++kc) {
                    int cc = 2 * pc2 - 1 + kc;
                    if ((unsigned)cc < 48u)
                        m = fmaxf(m, pbuf[(lr * 48 + cc) * 17 + oc]);
                }
            }
            f16 h = (f16)m;
            f16 lo = (f16)(m - (float)h);
            size_t off = (size_t)b * 36864 +
                         (size_t)((2 * g + pr2) * 24 + pc2) * 64 + og * 16 + oc;
            outh[off] = h;
            outl[off] = lo;
        }
        __syncthreads();
    }
}

// ---------------------------------------------------------------------------
// conv3x3 s1 p1 (64->64) + foldedBN (+res) + ReLU via f16-split MFMA.
// (unchanged, verified absmax 0)
// ---------------------------------------------------------------------------
template<int MODE, int OUTT>
__global__ __launch_bounds__(256) void conv3_mfma(
    const f16* __restrict__ inh, const f16* __restrict__ inl,
    const f16* __restrict__ wB,      // this layer's frag base (73728 halves)
    const float* __restrict__ bias,  // folded [64]
    const f16* __restrict__ resh, const f16* __restrict__ resl,
    f16* __restrict__ outh, f16* __restrict__ outl)
{
    __shared__ f16 lh[10 * 26 * 64];
    __shared__ f16 ll[10 * 26 * 64];
    const int r0 = blockIdx.x * 8;
    const int b  = blockIdx.y;
    const int tid = threadIdx.x;
    const int w = tid >> 6, l = tid & 63;
    const int l15 = l & 15, lg = l >> 4;

    for (int i = tid; i < 320; i += 256) {
        int arr = i >= 160; int c2 = i - arr * 160;
        int slot = c2 & 7; int pb = c2 >> 3;
        int lr = pb >> 1; int pc = (pb & 1) ? 25 : 0;
        int pix = lr * 26 + pc;
        int off = (pix * 128 + slot * 16) ^ ((pix & 7) << 4);
        *(uint4*)((arr ? (char*)ll : (char*)lh) + off) = make_uint4(0, 0, 0, 0);
    }
#pragma unroll
    for (int i = 0; i < 15; ++i) {
        int ch = tid + i * 256;
        int arr = ch >= 1920; int c2 = ch - arr * 1920;
        int slot = c2 & 7; int pix24 = c2 >> 3;
        int lr = pix24 / 24, pc = pix24 % 24;
        int ir = r0 - 1 + lr;
        uint4 v = make_uint4(0, 0, 0, 0);
        if ((unsigned)ir < 24u) {
            const f16* src = (arr ? inl : inh) +
                (((size_t)b * 576 + ir * 24 + pc) << 6) + slot * 8;
            v = *(const uint4*)(const void*)src;
        }
        int pix = lr * 26 + pc + 1;
        int off = (pix * 128 + slot * 16) ^ ((pix & 7) << 4);
        *(uint4*)((arr ? (char*)ll : (char*)lh) + off) = v;
    }

    int pr_[3], pc_[3];
#pragma unroll
    for (int mtl = 0; mtl < 3; ++mtl) {
        int lp = (w * 3 + mtl) * 16 + l15;
        pr_[mtl] = lp / 24; pc_[mtl] = lp % 24;
    }

    f32x4 acc[3][4];
#pragma unroll
    for (int m = 0; m < 3; ++m)
#pragma unroll
        for (int n = 0; n < 4; ++n) acc[m][n] = (f32x4){0.f, 0.f, 0.f, 0.f};

    __syncthreads();

#pragma unroll 1
    for (int tap = 0; tap < 9; ++tap) {
        int dr = tap / 3, dc = tap % 3;
#pragma unroll
        for (int kf = 0; kf < 2; ++kf) {
            const f16* wb = wB + (size_t)tap * 8192 + (size_t)kf * 1024 + (size_t)l * 8;
            f16x8 bh[4], bl[4];
#pragma unroll
            for (int nt = 0; nt < 4; ++nt) {
                bh[nt] = *(const f16x8*)(const void*)(wb + nt * 2048);
                bl[nt] = *(const f16x8*)(const void*)(wb + nt * 2048 + 512);
            }
#pragma unroll
            for (int mtl = 0; mtl < 3; ++mtl) {
                int pix = (pr_[mtl] + dr) * 26 + (pc_[mtl] + dc);
                int off = (pix * 128 + kf * 64 + lg * 16) ^ ((pix & 7) << 4);
                f16x8 ah = *(const f16x8*)((const char*)lh + off);
                f16x8 al = *(const f16x8*)((const char*)ll + off);
#pragma unroll
                for (int nt = 0; nt < 4; ++nt) {
                    acc[mtl][nt] = __builtin_amdgcn_mfma_f32_16x16x32_f16(ah, bh[nt], acc[mtl][nt], 0, 0, 0);
                    acc[mtl][nt] = __builtin_amdgcn_mfma_f32_16x16x32_f16(ah, bl[nt], acc[mtl][nt], 0, 0, 0);
                    acc[mtl][nt] = __builtin_amdgcn_mfma_f32_16x16x32_f16(al, bh[nt], acc[mtl][nt], 0, 0, 0);
                }
            }
        }
    }

    float bi[4];
#pragma unroll
    for (int nt = 0; nt < 4; ++nt) bi[nt] = bias[nt * 16 + l15];

#pragma unroll
    for (int mtl = 0; mtl < 3; ++mtl) {
#pragma unroll
        for (int nt = 0; nt < 4; ++nt) {
#pragma unroll
            for (int r = 0; r < 4; ++r) {
                int lp = (w * 3 + mtl) * 16 + lg * 4 + r;
                int p = r0 * 24 + lp;
                int oc = nt * 16 + l15;
                float v = acc[mtl][nt][r] + bi[nt];
                if (MODE) {
                    size_t ridx = (size_t)b * 36864 + (size_t)p * 64 + oc;
                    v += (float)resh[ridx] + (float)resl[ridx];
                }
                v = fmaxf(v, 0.f);
                f16 h = (f16)v;
                f16 lo = (f16)(v - (float)h);
                size_t oidx = OUTT ? ((size_t)b * 36864 + (size_t)oc * 576 + p)
                                   : ((size_t)b * 36864 + (size_t)p * 64 + oc);
                outh[oidx] = h;
                outl[oidx] = lo;
            }
        }
    }
}

// ---------------------------------------------------------------------------
// FC via f16-split MFMA (unchanged, verified)
// ---------------------------------------------------------------------------
#define FC_KSPLIT 32

__global__ __launch_bounds__(256) void fc_mfma(
    const f16* __restrict__ Ath, const f16* __restrict__ Atl,
    const float* __restrict__ Bw, float* __restrict__ part)
{
    __shared__ f16 As[2][128 * 40];
    __shared__ f16 Bs[2][16 * 40];
    const int nt = blockIdx.x;
    const int ks = blockIdx.y;
    const int tid = threadIdx.x;
    const int w = tid >> 6, l = tid & 63;
    const int l15 = l & 15, lg = l >> 4;
    const int k0b = ks * 1152;

    f32x4 acc[2];
    acc[0] = (f32x4){0.f, 0.f, 0.f, 0.f};
    acc[1] = (f32x4){0.f, 0.f, 0.f, 0.f};

    const int bn = tid >> 4, bkl = (tid & 15) * 2;
#pragma unroll 1
    for (int st = 0; st < 36; ++st) {
        int k0 = k0b + st * 32;
        __syncthreads();
#pragma unroll
        for (int i = 0; i < 4; ++i) {
            int ch = tid + i * 256;
            int arr = ch >= 512; int c2 = ch - arr * 512;
            int m = c2 >> 2, slot = c2 & 3;
            const f16* src = (arr ? Atl : Ath) + (size_t)m * 36864 + k0 + slot * 8;
            *(uint4*)(void*)&As[arr][m * 40 + slot * 8] = *(const uint4*)(const void*)src;
        }
        {
            float2 f2 = *(const float2*)&Bw[(size_t)(nt * 16 + bn) * 36864 + k0 + bkl];
            f16 h0 = (f16)f2.x, h1 = (f16)f2.y;
            Bs[0][bn * 40 + bkl] = h0;     Bs[0][bn * 40 + bkl + 1] = h1;
            Bs[1][bn * 40 + bkl] = (f16)(f2.x - (float)h0);
            Bs[1][bn * 40 + bkl + 1] = (f16)(f2.y - (float)h1);
        }
        __syncthreads();
        f16x8 bh = *(const f16x8*)(const void*)&Bs[0][l15 * 40 + lg * 8];
        f16x8 bl = *(const f16x8*)(const void*)&Bs[1][l15 * 40 + lg * 8];
#pragma unroll
        for (int mtl = 0; mtl < 2; ++mtl) {
            int m = w * 32 + mtl * 16 + l15;
            f16x8 ah = *(const f16x8*)(const void*)&As[0][m * 40 + lg * 8];
            f16x8 al = *(const f16x8*)(const void*)&As[1][m * 40 + lg * 8];
            acc[mtl] = __builtin_amdgcn_mfma_f32_16x16x32_f16(ah, bh, acc[mtl], 0, 0, 0);
            acc[mtl] = __builtin_amdgcn_mfma_f32_16x16x32_f16(ah, bl, acc[mtl], 0, 0, 0);
            acc[mtl] = __builtin_amdgcn_mfma_f32_16x16x32_f16(al, bh, acc[mtl], 0, 0, 0);
        }
    }
#pragma unroll
    for (int mtl = 0; mtl < 2; ++mtl)
#pragma unroll
        for (int r = 0; r < 4; ++r) {
            int m = w * 32 + mtl * 16 + lg * 4 + r;
            int n = nt * 16 + l15;
            part[((size_t)ks * 128 + m) * 144 + n] = acc[mtl][r];
        }
}

__global__ __launch_bounds__(256) void fc_reduce(
    const float* __restrict__ part, const float* __restrict__ bias,
    float* __restrict__ costs)
{
    int idx = blockIdx.x * 256 + threadIdx.x;
    if (idx >= 128 * 144) return;
    float sum = bias[idx % 144];
    for (int s = 0; s < FC_KSPLIT; ++s) sum += part[(size_t)s * (128 * 144) + idx];
    costs[idx] = sum;
}

// ---------------------------------------------------------------------------
// Bellman-Ford v6: wave-synchronous LDS. 1 sample per single-wave block
// (128 blocks x 64 thr): dist in BIG-padded [14][14] LDS (double-buffered by
// index toggle), lane owns cells {l, l+64, l+128<144}. No barriers, no DPP:
// within one wave, LDS op ordering (+volatile) guarantees Jacobi semantics.
// Padded border = BIG reproduces the reference's out-of-grid handling.
// ---------------------------------------------------------------------------
__global__ __launch_bounds__(64) void shortest_path(
    const float* __restrict__ costs, float* __restrict__ out)
{
    __shared__ float dbuf[2][196];     // [14][14] padded, double-buffered
    __shared__ float msk[144];
    const int s = blockIdx.x;
    const int l = threadIdx.x;
    volatile float* b0 = &dbuf[0][0];
    volatile float* b1 = &dbuf[1][0];
    volatile float* vm = &msk[0];

    // init everything (pads + interior) to BIG; mask to 0
    for (int k = l; k < 196; k += 64) { b0[k] = BIGF; b1[k] = BIGF; }
    for (int k = l; k < 144; k += 64) vm[k] = 0.f;

    const int m0 = l, m1 = l + 64, m2 = l + 128;
    const bool has2 = (l < 16);
    const int p0 = (m0 / 12 + 1) * 14 + (m0 % 12 + 1);
    const int p1 = (m1 / 12 + 1) * 14 + (m1 % 12 + 1);
    const int p2 = (m2 / 12 + 1) * 14 + (m2 % 12 + 1);

    const float* cp = costs + s * 144;
    float cc0 = cp[m0];
    float cc1 = cp[m1];
    float cc2 = has2 ? cp[m2] : BIGF;

    float dd0 = (l == 0) ? cc0 : BIGF;   // dist[0,0] = costs[0,0]
    float dd1 = BIGF, dd2 = BIGF;
    if (l == 0) b0[15] = dd0;            // (0,0) -> padded idx 1*14+1

    int cur = 0;
#pragma unroll 1
    for (int it = 0; it < 144; ++it) {
        volatile float* cb = &dbuf[cur][0];
        volatile float* nb = &dbuf[cur ^ 1][0];
        float u0 = cb[p0 - 14], dn0 = cb[p0 + 14], lf0 = cb[p0 - 1], rt0 = cb[p0 + 1];
        float u1 = cb[p1 - 14], dn1 = cb[p1 + 14], lf1 = cb[p1 - 1], rt1 = cb[p1 + 1];
        float u2 = BIGF, dn2 = BIGF, lf2 = BIGF, rt2 = BIGF;
        if (has2) { u2 = cb[p2 - 14]; dn2 = cb[p2 + 14]; lf2 = cb[p2 - 1]; rt2 = cb[p2 + 1]; }
        dd0 = fminf(dd0, fminf(fminf(u0, dn0), fminf(lf0, rt0)) + cc0);
        dd1 = fminf(dd1, fminf(fminf(u1, dn1), fminf(lf1, rt1)) + cc1);
        if (has2) dd2 = fminf(dd2, fminf(fminf(u2, dn2), fminf(lf2, rt2)) + cc2);
        nb[p0] = dd0;
        nb[p1] = dd1;
        if (has2) nb[p2] = dd2;
        cur ^= 1;
    }

    // serial greedy backtrack on lane 0 (pads give BIG for out-of-grid)
    if (l == 0) {
        volatile float* fb = &dbuf[cur][0];
        int pi = 11, pj = 11;
#pragma unroll 1
        for (int it = 0; it < 144; ++it) {
            vm[pi * 12 + pj] = 1.f;
            if (pi == 0 && pj == 0) break;   // further ref iters are no-ops
            float vu = fb[pi * 14 + pj + 1];          // (pi-1, pj)
            float vd = fb[(pi + 2) * 14 + pj + 1];    // (pi+1, pj)
            float vl = fb[(pi + 1) * 14 + pj];        // (pi, pj-1)
            float vr = fb[(pi + 1) * 14 + pj + 2];    // (pi, pj+1)
            float best = vu; int kb = 0;              // first-min: up,down,left,right
            if (vd < best) { best = vd; kb = 1; }
            if (vl < best) { best = vl; kb = 2; }
            if (vr < best) { best = vr; kb = 3; }
            pi += (kb == 0) ? -1 : (kb == 1) ? 1 : 0;
            pj += (kb == 2) ? -1 : (kb == 3) ? 1 : 0;
        }
    }

    // same wave: lane-0's mask writes ordered before these reads
    out[s * 144 + m0] = vm[m0];
    out[s * 144 + m1] = vm[m1];
    if (has2) out[s * 144 + m2] = vm[m2];
}

// ---------------------------------------------------------------------------
extern "C" void kernel_launch(void* const* d_in, const int* in_sizes, int n_in,
                              void* d_out, int out_size, void* d_ws, size_t ws_size,
                              hipStream_t stream) {
    const float* x    = (const float*)d_in[0];
    const float* c1w  = (const float*)d_in[1];
    const float* bn1g = (const float*)d_in[2];
    const float* bn1b = (const float*)d_in[3];
    const float* bn1m = (const float*)d_in[4];
    const float* bn1v = (const float*)d_in[5];
    const float* blkw = (const float*)d_in[6];
    const float* blkg = (const float*)d_in[7];
    const float* blkb = (const float*)d_in[8];
    const float* blkm = (const float*)d_in[9];
    const float* blkv = (const float*)d_in[10];
    const float* fcw  = (const float*)d_in[11];
    const float* fcb  = (const float*)d_in[12];
    float* out = (float*)d_out;
    char* ws = (char*)d_ws;

    const size_t APL = 9437184;            // 128*36864 halves * 2B
    f16* a0h = (f16*)(ws);
    f16* a0l = (f16*)(ws + APL);
    f16* a1h = (f16*)(ws + 2 * APL);
    f16* a1l = (f16*)(ws + 3 * APL);
    f16* a2h = (f16*)(ws + 4 * APL);
    f16* a2l = (f16*)(ws + 5 * APL);
    float* costs = (float*)(ws + 6 * APL);                       // 73728 B
    float* part  = (float*)(ws + 6 * APL + 73728);               // 2359296 B
    f16*   wB    = (f16*)  (ws + 6 * APL + 73728 + 2359296);     // 589824 B
    float* b3    = (float*)(ws + 6 * APL + 73728 + 2359296 + 589824);       // 1024 B
    float* b1    = (float*)(ws + 6 * APL + 73728 + 2359296 + 589824 + 1024);// 256 B
    f16*   wB1   = (f16*)  (ws + 6 * APL + 73728 + 2359296 + 589824 + 1280);// 57344 B

    prepack<<<dim3(690), dim3(256), 0, stream>>>(
        c1w, bn1g, bn1b, bn1m, bn1v, blkw, blkg, blkb, blkm, blkv,
        wB, wB1, b3, b1);

    conv1_mfma<<<dim3(12, 128), dim3(256), 0, stream>>>(x, wB1, b1, a0h, a0l);

    // per-layer frag stride = 9 taps * 4 nt * 2 kf * 2 hl * 512 = 73728 halves
    conv3_mfma<0, 0><<<dim3(3, 128), dim3(256), 0, stream>>>(
        a0h, a0l, wB + 0 * 73728, b3 + 0,   nullptr, nullptr, a1h, a1l);
    conv3_mfma<1, 0><<<dim3(3, 128), dim3(256), 0, stream>>>(
        a1h, a1l, wB + 1 * 73728, b3 + 64,  a0h, a0l, a2h, a2l);
    conv3_mfma<0, 0><<<dim3(3, 128), dim3(256), 0, stream>>>(
        a2h, a2l, wB + 2 * 73728, b3 + 128, nullptr, nullptr, a1h, a1l);
    conv3_mfma<1, 1><<<dim3(3, 128), dim3(256), 0, stream>>>(
        a1h, a1l, wB + 3 * 73728, b3 + 192, a2h, a2l, a0h, a0l);  // NCHW-T out

    fc_mfma<<<dim3(9, FC_KSPLIT), dim3(256), 0, stream>>>(a0h, a0l, fcw, part);
    fc_reduce<<<dim3(72), dim3(256), 0, stream>>>(part, fcb, costs);
    shortest_path<<<dim3(128), dim3(64), 0, stream>>>(costs, out);
}

// Round 15
// 238.158 us; speedup vs baseline: 1.2672x; 1.2672x over previous
//
#include <hip/hip_runtime.h>
#include <math.h>

#define BIGF 1e10f
#define EPSF 1e-5f

typedef _Float16 f16;
typedef f16 f16x8 __attribute__((ext_vector_type(8)));
typedef float f32x4 __attribute__((ext_vector_type(4)));

static __device__ __forceinline__ f16x8 mk8(uint a, uint b, uint c, uint d) {
    union { uint u[4]; f16x8 v; } t;
    t.u[0] = a; t.u[1] = b; t.u[2] = c; t.u[3] = d;
    return t.v;
}

// ---------------------------------------------------------------------------
// Prepack (unchanged, verified)
// ---------------------------------------------------------------------------
__global__ __launch_bounds__(256) void prepack(
    const float* __restrict__ c1w,
    const float* __restrict__ bn1g, const float* __restrict__ bn1b,
    const float* __restrict__ bn1m, const float* __restrict__ bn1v,
    const float* __restrict__ blkw,
    const float* __restrict__ blkg, const float* __restrict__ blkb,
    const float* __restrict__ blkm, const float* __restrict__ blkv,
    f16* __restrict__ wB, f16* __restrict__ wB1,
    float* __restrict__ b3, float* __restrict__ b1)
{
    int idx = blockIdx.x * 256 + threadIdx.x;
    if (idx < 147456) {                    // conv3 weight frags
        int pos = idx;
        int j    = pos & 7;
        int lane = (pos >> 3) & 63;
        int rest = pos >> 9;               // (((layer*9+tap)*4+nt)*2+kf)
        int kf   = rest & 1;
        int r2   = rest >> 1;
        int ntl  = r2 & 3;
        int r3   = r2 >> 2;
        int tap  = r3 % 9;
        int layer= r3 / 9;
        int ic = kf * 32 + (lane >> 4) * 8 + j;
        int oc = ntl * 16 + (lane & 15);
        float s = blkg[layer * 64 + oc] * rsqrtf(blkv[layer * 64 + oc] + EPSF);
        float wv = blkw[(((size_t)layer * 64 + oc) * 64 + ic) * 9 + tap] * s;
        f16 h = (f16)wv;
        f16 lo = (f16)(wv - (float)h);
        int low9 = pos & 511;
        wB[(size_t)rest * 1024 + low9]       = h;
        wB[(size_t)rest * 1024 + 512 + low9] = lo;
    }
    int q = idx - 147456;
    if (q >= 0 && q < 28672) {             // conv1 frags
        int j = q & 7, lane = (q >> 3) & 63, rest = q >> 9;  // ((kh*4+nt)*2+hl)
        int hl = rest & 1, nt = (rest >> 1) & 3, kh = rest >> 3;
        int oc = nt * 16 + (lane & 15), lgq = lane >> 4;
        float v = 0.f;
        if (lgq < 3 && j < 7) {
            float s = bn1g[oc] * rsqrtf(bn1v[oc] + EPSF);
            v = c1w[((oc * 3 + lgq) * 7 + kh) * 7 + j] * s;
        }
        f16 h = (f16)v;
        wB1[q] = hl ? (f16)(v - (float)h) : h;
    }
    int k = idx - 147456 - 28672;
    if (k >= 0 && k < 256) {
        float s = blkg[k] * rsqrtf(blkv[k] + EPSF);
        b3[k] = blkb[k] - blkm[k] * s;
    }
    int l = idx - 147456 - 28672 - 256;
    if (l >= 0 && l < 64) {
        float s = bn1g[l] * rsqrtf(bn1v[l] + EPSF);
        b1[l] = bn1b[l] - bn1m[l] * s;
    }
}

// ---------------------------------------------------------------------------
// conv1 7x7 s2 p3 + foldedBN + ReLU + maxpool via f16-split MFMA.
// (R9-verified, unchanged)
// ---------------------------------------------------------------------------
__global__ __launch_bounds__(256) void conv1_mfma(
    const float* __restrict__ x, const f16* __restrict__ wB1,
    const float* __restrict__ bias,
    f16* __restrict__ outh, f16* __restrict__ outl)
{
    __shared__ char lds[18720];
    const int g = blockIdx.x, b = blockIdx.y;
    const int tid = threadIdx.x;
    const int w = tid >> 6, l = tid & 63;
    const int l15 = l & 15, lg = l >> 4;

    for (int i = tid; i < 4680; i += 256) ((uint*)lds)[i] = 0u;
    __syncthreads();
    const int ir0 = 8 * g - 5;
    const float* xb = x + (size_t)b * 27648;
    for (int u = tid; u < 2205; u += 256) {
        int cu = 1 + (u % 49);
        int rr = (u / 49) % 15;
        int ic = u / 735;
        int ir = ir0 + rr;
        uint pk_h = 0u, pk_l = 0u;
        if ((unsigned)ir < 96u) {
            int c0i = 2 * cu - 3, c1i = 2 * cu - 2;
            const float* rowp = xb + ic * 9216 + ir * 96;
            float v0 = (c0i >= 0) ? rowp[c0i] : 0.f;
            float v1 = (c1i <= 95) ? rowp[c1i] : 0.f;
            f16 h0 = (f16)v0; f16 lo0 = (f16)(v0 - (float)h0);
            f16 h1 = (f16)v1; f16 lo1 = (f16)(v1 - (float)h1);
            union { f16 f[2]; uint u32; } ph, pl;
            ph.f[0] = h0;  ph.f[1] = h1;  pk_h = ph.u32;
            pl.f[0] = lo0; pl.f[1] = lo1; pk_l = pl.u32;
        }
        int off = ic * 3120 + rr * 208 + 4 * cu;
        *(uint*)(lds + off) = pk_h;
        *(uint*)(lds + 9360 + off) = pk_l;
    }
    __syncthreads();

    f32x4 acc[4][4];
#pragma unroll
    for (int k = 0; k < 4; ++k)
#pragma unroll
        for (int nt = 0; nt < 4; ++nt) acc[k][nt] = (f32x4){0.f, 0.f, 0.f, 0.f};

    const int icB = (lg >= 3 ? 0 : lg) * 3120;
    const char* hbase = lds + icB;
    const char* lbase = lds + 9360 + icB;
    const f16* wq = wB1 + (size_t)l * 8;

    int rowoff[4], aoff[4];
#pragma unroll
    for (int k = 0; k < 4; ++k) {
        int t = w + 4 * k;
        int tt = (t < 15) ? t : 0;
        rowoff[k] = tt / 3;
        aoff[k] = 4 * ((tt % 3) * 16 + l15);
    }

#pragma unroll 1
    for (int kh = 0; kh < 7; ++kh) {
        const f16* wk = wq + kh * 4096;
        f16x8 bq[4];
#pragma unroll
        for (int nt = 0; nt < 4; ++nt)
            bq[nt] = *(const f16x8*)(const void*)(wk + nt * 1024);
#pragma unroll
        for (int k = 0; k < 4; ++k) {
            if (w + 4 * k < 15) {
                int ro = (2 * rowoff[k] + kh) * 208 + aoff[k];
                const uint* ph = (const uint*)(hbase + ro);
                const uint* pl = (const uint*)(lbase + ro);
                f16x8 ah = mk8(ph[0], ph[1], ph[2], ph[3]);
                f16x8 al = mk8(pl[0], pl[1], pl[2], pl[3]);
#pragma unroll
                for (int nt = 0; nt < 4; ++nt) {
                    acc[k][nt] = __builtin_amdgcn_mfma_f32_16x16x32_f16(ah, bq[nt], acc[k][nt], 0, 0, 0);
                    acc[k][nt] = __builtin_amdgcn_mfma_f32_16x16x32_f16(al, bq[nt], acc[k][nt], 0, 0, 0);
                }
            }
        }
#pragma unroll
        for (int nt = 0; nt < 4; ++nt)
            bq[nt] = *(const f16x8*)(const void*)(wk + nt * 1024 + 512);
#pragma unroll
        for (int k = 0; k < 4; ++k) {
            if (w + 4 * k < 15) {
                int ro = (2 * rowoff[k] + kh) * 208 + aoff[k];
                const uint* ph = (const uint*)(hbase + ro);
                f16x8 ah = mk8(ph[0], ph[1], ph[2], ph[3]);
#pragma unroll
                for (int nt = 0; nt < 4; ++nt)
                    acc[k][nt] = __builtin_amdgcn_mfma_f32_16x16x32_f16(ah, bq[nt], acc[k][nt], 0, 0, 0);
            }
        }
    }

    __syncthreads();
    float* pbuf = (float*)(void*)lds;
#pragma unroll
    for (int og = 0; og < 4; ++og) {
        float bi = bias[og * 16 + l15];
#pragma unroll
        for (int k = 0; k < 4; ++k) {
            int t = w + 4 * k;
            if (t < 15) {
                int lr = t / 3;
                int c0 = (t % 3) * 16;
#pragma unroll
                for (int r = 0; r < 4; ++r) {
                    int col = c0 + lg * 4 + r;
                    pbuf[(lr * 48 + col) * 17 + l15] = fmaxf(acc[k][og][r] + bi, 0.f);
                }
            }
        }
        __syncthreads();
#pragma unroll
        for (int it = 0; it < 3; ++it) {
            int idx = tid + it * 256;
            int oc = idx & 15, p2 = idx >> 4;
            int pc2 = p2 % 24, pr2 = p2 / 24;
            float m = -INFINITY;
#pragma unroll
            for (int kr = 0; kr < 3; ++kr) {
                int lr = 2 * pr2 + kr;
                if (g == 0 && lr == 0) continue;
#pragma unroll
                for (int kc = 0; kc < 3; ++kc) {
                    int cc = 2 * pc2 - 1 + kc;
                    if ((unsigned)cc < 48u)
                        m = fmaxf(m, pbuf[(lr * 48 + cc) * 17 + oc]);
                }
            }
            f16 h = (f16)m;
            f16 lo = (f16)(m - (float)h);
            size_t off = (size_t)b * 36864 +
                         (size_t)((2 * g + pr2) * 24 + pc2) * 64 + og * 16 + oc;
            outh[off] = h;
            outl[off] = lo;
        }
        __syncthreads();
    }
}

// ---------------------------------------------------------------------------
// conv3x3 s1 p1 (64->64) + foldedBN (+res) + ReLU via f16-split MFMA, v2:
// 4-row blocks. Grid (6,128) = 768 blocks = exactly 3/CU (was 384 = 1.5/CU
// -> 25% residency tail). Block: output rows 4gx..4gx+3 (6 M-tiles), staged
// rows 4gx-1..4gx+4 (6 rows), LDS 39.9 KB. Wave w owns tiles {w, w+4(<6)}.
// Fragment math / swizzle identical to the verified 8-row version.
// ---------------------------------------------------------------------------
template<int MODE, int OUTT>
__global__ __launch_bounds__(256) void conv3_mfma(
    const f16* __restrict__ inh, const f16* __restrict__ inl,
    const f16* __restrict__ wB,      // this layer's frag base (73728 halves)
    const float* __restrict__ bias,  // folded [64]
    const f16* __restrict__ resh, const f16* __restrict__ resl,
    f16* __restrict__ outh, f16* __restrict__ outl)
{
    __shared__ f16 lh[6 * 26 * 64];
    __shared__ f16 ll[6 * 26 * 64];
    const int r0 = blockIdx.x * 4;
    const int b  = blockIdx.y;
    const int tid = threadIdx.x;
    const int w = tid >> 6, l = tid & 63;
    const int l15 = l & 15, lg = l >> 4;

    // zero border cols (pc = 0, 25): 2 arrays x 6 rows x 2 cols x 8 slots
    if (tid < 192) {
        int arr = tid >= 96; int c2 = tid - arr * 96;
        int slot = c2 & 7; int pb = c2 >> 3;          // 0..11
        int lr = pb >> 1; int pc = (pb & 1) ? 25 : 0;
        int pix = lr * 26 + pc;
        int off = (pix * 128 + slot * 16) ^ ((pix & 7) << 4);
        *(uint4*)((arr ? (char*)ll : (char*)lh) + off) = make_uint4(0, 0, 0, 0);
    }
    // interior staging: 2304 chunks (2 arrays x 6 rows x 24 cols x 8 slots)
#pragma unroll
    for (int i = 0; i < 9; ++i) {
        int ch = tid + i * 256;
        int arr = ch >= 1152; int c2 = ch - arr * 1152;
        int slot = c2 & 7; int pix24 = c2 >> 3;        // 0..143
        int lr = pix24 / 24, pc = pix24 % 24;
        int ir = r0 - 1 + lr;
        uint4 v = make_uint4(0, 0, 0, 0);
        if ((unsigned)ir < 24u) {
            const f16* src = (arr ? inl : inh) +
                (((size_t)b * 576 + ir * 24 + pc) << 6) + slot * 8;
            v = *(const uint4*)(const void*)src;
        }
        int pix = lr * 26 + pc + 1;
        int off = (pix * 128 + slot * 16) ^ ((pix & 7) << 4);
        *(uint4*)((arr ? (char*)ll : (char*)lh) + off) = v;
    }

    // wave w -> tiles w and w+4 (second valid only for w<2)
    int pr_[2], pc_[2];
#pragma unroll
    for (int mtl = 0; mtl < 2; ++mtl) {
        int t = w + 4 * mtl;
        int tt = (t < 6) ? t : 0;
        int lp = tt * 16 + l15;
        pr_[mtl] = lp / 24; pc_[mtl] = lp % 24;
    }

    f32x4 acc[2][4];
#pragma unroll
    for (int m = 0; m < 2; ++m)
#pragma unroll
        for (int n = 0; n < 4; ++n) acc[m][n] = (f32x4){0.f, 0.f, 0.f, 0.f};

    __syncthreads();

#pragma unroll 1
    for (int tap = 0; tap < 9; ++tap) {
        int dr = tap / 3, dc = tap % 3;
#pragma unroll
        for (int kf = 0; kf < 2; ++kf) {
            const f16* wb = wB + (size_t)tap * 8192 + (size_t)kf * 1024 + (size_t)l * 8;
            f16x8 bh[4], bl[4];
#pragma unroll
            for (int nt = 0; nt < 4; ++nt) {
                bh[nt] = *(const f16x8*)(const void*)(wb + nt * 2048);
                bl[nt] = *(const f16x8*)(const void*)(wb + nt * 2048 + 512);
            }
#pragma unroll
            for (int mtl = 0; mtl < 2; ++mtl) {
                if (mtl == 1 && w >= 2) continue;
                int pix = (pr_[mtl] + dr) * 26 + (pc_[mtl] + dc);
                int off = (pix * 128 + kf * 64 + lg * 16) ^ ((pix & 7) << 4);
                f16x8 ah = *(const f16x8*)((const char*)lh + off);
                f16x8 al = *(const f16x8*)((const char*)ll + off);
#pragma unroll
                for (int nt = 0; nt < 4; ++nt) {
                    acc[mtl][nt] = __builtin_amdgcn_mfma_f32_16x16x32_f16(ah, bh[nt], acc[mtl][nt], 0, 0, 0);
                    acc[mtl][nt] = __builtin_amdgcn_mfma_f32_16x16x32_f16(ah, bl[nt], acc[mtl][nt], 0, 0, 0);
                    acc[mtl][nt] = __builtin_amdgcn_mfma_f32_16x16x32_f16(al, bh[nt], acc[mtl][nt], 0, 0, 0);
                }
            }
        }
    }

    float bi[4];
#pragma unroll
    for (int nt = 0; nt < 4; ++nt) bi[nt] = bias[nt * 16 + l15];

#pragma unroll
    for (int mtl = 0; mtl < 2; ++mtl) {
        if (mtl == 1 && w >= 2) continue;
        int t = w + 4 * mtl;
#pragma unroll
        for (int nt = 0; nt < 4; ++nt) {
#pragma unroll
            for (int r = 0; r < 4; ++r) {
                int lp = t * 16 + lg * 4 + r;
                int p = r0 * 24 + lp;                   // pixel 0..575
                int oc = nt * 16 + l15;
                float v = acc[mtl][nt][r] + bi[nt];
                if (MODE) {
                    size_t ridx = (size_t)b * 36864 + (size_t)p * 64 + oc;
                    v += (float)resh[ridx] + (float)resl[ridx];
                }
                v = fmaxf(v, 0.f);
                f16 h = (f16)v;
                f16 lo = (f16)(v - (float)h);
                size_t oidx = OUTT ? ((size_t)b * 36864 + (size_t)oc * 576 + p)
                                   : ((size_t)b * 36864 + (size_t)p * 64 + oc);
                outh[oidx] = h;
                outl[oidx] = lo;
            }
        }
    }
}

// ---------------------------------------------------------------------------
// FC via f16-split MFMA (unchanged, verified)
// ---------------------------------------------------------------------------
#define FC_KSPLIT 32

__global__ __launch_bounds__(256) void fc_mfma(
    const f16* __restrict__ Ath, const f16* __restrict__ Atl,
    const float* __restrict__ Bw, float* __restrict__ part)
{
    __shared__ f16 As[2][128 * 40];
    __shared__ f16 Bs[2][16 * 40];
    const int nt = blockIdx.x;
    const int ks = blockIdx.y;
    const int tid = threadIdx.x;
    const int w = tid >> 6, l = tid & 63;
    const int l15 = l & 15, lg = l >> 4;
    const int k0b = ks * 1152;

    f32x4 acc[2];
    acc[0] = (f32x4){0.f, 0.f, 0.f, 0.f};
    acc[1] = (f32x4){0.f, 0.f, 0.f, 0.f};

    const int bn = tid >> 4, bkl = (tid & 15) * 2;
#pragma unroll 1
    for (int st = 0; st < 36; ++st) {
        int k0 = k0b + st * 32;
        __syncthreads();
#pragma unroll
        for (int i = 0; i < 4; ++i) {
            int ch = tid + i * 256;
            int arr = ch >= 512; int c2 = ch - arr * 512;
            int m = c2 >> 2, slot = c2 & 3;
            const f16* src = (arr ? Atl : Ath) + (size_t)m * 36864 + k0 + slot * 8;
            *(uint4*)(void*)&As[arr][m * 40 + slot * 8] = *(const uint4*)(const void*)src;
        }
        {
            float2 f2 = *(const float2*)&Bw[(size_t)(nt * 16 + bn) * 36864 + k0 + bkl];
            f16 h0 = (f16)f2.x, h1 = (f16)f2.y;
            Bs[0][bn * 40 + bkl] = h0;     Bs[0][bn * 40 + bkl + 1] = h1;
            Bs[1][bn * 40 + bkl] = (f16)(f2.x - (float)h0);
            Bs[1][bn * 40 + bkl + 1] = (f16)(f2.y - (float)h1);
        }
        __syncthreads();
        f16x8 bh = *(const f16x8*)(const void*)&Bs[0][l15 * 40 + lg * 8];
        f16x8 bl = *(const f16x8*)(const void*)&Bs[1][l15 * 40 + lg * 8];
#pragma unroll
        for (int mtl = 0; mtl < 2; ++mtl) {
            int m = w * 32 + mtl * 16 + l15;
            f16x8 ah = *(const f16x8*)(const void*)&As[0][m * 40 + lg * 8];
            f16x8 al = *(const f16x8*)(const void*)&As[1][m * 40 + lg * 8];
            acc[mtl] = __builtin_amdgcn_mfma_f32_16x16x32_f16(ah, bh, acc[mtl], 0, 0, 0);
            acc[mtl] = __builtin_amdgcn_mfma_f32_16x16x32_f16(ah, bl, acc[mtl], 0, 0, 0);
            acc[mtl] = __builtin_amdgcn_mfma_f32_16x16x32_f16(al, bh, acc[mtl], 0, 0, 0);
        }
    }
#pragma unroll
    for (int mtl = 0; mtl < 2; ++mtl)
#pragma unroll
        for (int r = 0; r < 4; ++r) {
            int m = w * 32 + mtl * 16 + lg * 4 + r;
            int n = nt * 16 + l15;
            part[((size_t)ks * 128 + m) * 144 + n] = acc[mtl][r];
        }
}

__global__ __launch_bounds__(256) void fc_reduce(
    const float* __restrict__ part, const float* __restrict__ bias,
    float* __restrict__ costs)
{
    int idx = blockIdx.x * 256 + threadIdx.x;
    if (idx >= 128 * 144) return;
    float sum = bias[idx % 144];
    for (int s = 0; s < FC_KSPLIT; ++s) sum += part[(size_t)s * (128 * 144) + idx];
    costs[idx] = sum;
}

// ---------------------------------------------------------------------------
// Bellman-Ford + greedy backtrack: EXACT R9 version (53 us, proven best of
// 6 variants; all register/DPP/volatile alternatives measured slower).
// ---------------------------------------------------------------------------
__global__ __launch_bounds__(192) void shortest_path(
    const float* __restrict__ costs, float* __restrict__ out)
{
    __shared__ float dA[144], dB[144], cs[144], mask[144];
    const int b = blockIdx.x, tid = threadIdx.x;
    if (tid < 144) {
        float c = costs[b * 144 + tid];
        cs[tid] = c;
        dA[tid] = (tid == 0) ? c : BIGF;
        mask[tid] = 0.f;
    }
    __syncthreads();
    float* cur = dA; float* nxt = dB;
    for (int it = 0; it < 144; ++it) {
        if (tid < 144) {
            int i = tid / 12, j = tid % 12;
            float up = (i > 0)  ? cur[tid - 12] : BIGF;
            float dn = (i < 11) ? cur[tid + 12] : BIGF;
            float lf = (j > 0)  ? cur[tid - 1]  : BIGF;
            float rt = (j < 11) ? cur[tid + 1]  : BIGF;
            float nb = fminf(fminf(up, dn), fminf(lf, rt));
            nxt[tid] = fminf(cur[tid], nb + cs[tid]);
        }
        __syncthreads();
        float* tp = cur; cur = nxt; nxt = tp;
    }
    if (tid == 0) {
        int i = 11, j = 11;
        const int di[4] = {-1, 1, 0, 0};
        const int dj[4] = {0, 0, -1, 1};
        for (int it = 0; it < 144; ++it) {
            mask[i * 12 + j] = 1.f;
            float vals[4];
#pragma unroll
            for (int k = 0; k < 4; ++k) {
                int ni = i + di[k], nj = j + dj[k];
                bool valid = (ni >= 0) && (ni < 12) && (nj >= 0) && (nj < 12);
                vals[k] = valid ? cur[ni * 12 + nj] : BIGF;
            }
            float best = vals[0]; int kb = 0;
#pragma unroll
            for (int k = 1; k < 4; ++k)
                if (vals[k] < best) { best = vals[k]; kb = k; }
            if (!(i == 0 && j == 0)) { i += di[kb]; j += dj[kb]; }
        }
    }
    __syncthreads();
    if (tid < 144) out[b * 144 + tid] = mask[tid];
}

// ---------------------------------------------------------------------------
extern "C" void kernel_launch(void* const* d_in, const int* in_sizes, int n_in,
                              void* d_out, int out_size, void* d_ws, size_t ws_size,
                              hipStream_t stream) {
    const float* x    = (const float*)d_in[0];
    const float* c1w  = (const float*)d_in[1];
    const float* bn1g = (const float*)d_in[2];
    const float* bn1b = (const float*)d_in[3];
    const float* bn1m = (const float*)d_in[4];
    const float* bn1v = (const float*)d_in[5];
    const float* blkw = (const float*)d_in[6];
    const float* blkg = (const float*)d_in[7];
    const float* blkb = (const float*)d_in[8];
    const float* blkm = (const float*)d_in[9];
    const float* blkv = (const float*)d_in[10];
    const float* fcw  = (const float*)d_in[11];
    const float* fcb  = (const float*)d_in[12];
    float* out = (float*)d_out;
    char* ws = (char*)d_ws;

    const size_t APL = 9437184;            // 128*36864 halves * 2B
    f16* a0h = (f16*)(ws);
    f16* a0l = (f16*)(ws + APL);
    f16* a1h = (f16*)(ws + 2 * APL);
    f16* a1l = (f16*)(ws + 3 * APL);
    f16* a2h = (f16*)(ws + 4 * APL);
    f16* a2l = (f16*)(ws + 5 * APL);
    float* costs = (float*)(ws + 6 * APL);                       // 73728 B
    float* part  = (float*)(ws + 6 * APL + 73728);               // 2359296 B
    f16*   wB    = (f16*)  (ws + 6 * APL + 73728 + 2359296);     // 589824 B
    float* b3    = (float*)(ws + 6 * APL + 73728 + 2359296 + 589824);       // 1024 B
    float* b1    = (float*)(ws + 6 * APL + 73728 + 2359296 + 589824 + 1024);// 256 B
    f16*   wB1   = (f16*)  (ws + 6 * APL + 73728 + 2359296 + 589824 + 1280);// 57344 B

    prepack<<<dim3(690), dim3(256), 0, stream>>>(
        c1w, bn1g, bn1b, bn1m, bn1v, blkw, blkg, blkb, blkm, blkv,
        wB, wB1, b3, b1);

    conv1_mfma<<<dim3(12, 128), dim3(256), 0, stream>>>(x, wB1, b1, a0h, a0l);

    // per-layer frag stride = 9 taps * 4 nt * 2 kf * 2 hl * 512 = 73728 halves
    conv3_mfma<0, 0><<<dim3(6, 128), dim3(256), 0, stream>>>(
        a0h, a0l, wB + 0 * 73728, b3 + 0,   nullptr, nullptr, a1h, a1l);
    conv3_mfma<1, 0><<<dim3(6, 128), dim3(256), 0, stream>>>(
        a1h, a1l, wB + 1 * 73728, b3 + 64,  a0h, a0l, a2h, a2l);
    conv3_mfma<0, 0><<<dim3(6, 128), dim3(256), 0, stream>>>(
        a2h, a2l, wB + 2 * 73728, b3 + 128, nullptr, nullptr, a1h, a1l);
    conv3_mfma<1, 1><<<dim3(6, 128), dim3(256), 0, stream>>>(
        a1h, a1l, wB + 3 * 73728, b3 + 192, a2h, a2l, a0h, a0l);  // NCHW-T out

    fc_mfma<<<dim3(9, FC_KSPLIT), dim3(256), 0, stream>>>(a0h, a0l, fcw, part);
    fc_reduce<<<dim3(72), dim3(256), 0, stream>>>(part, fcb, costs);
    shortest_path<<<dim3(128), dim3(192), 0, stream>>>(costs, out);
}